// Round 9
// baseline (278.792 us; speedup 1.0000x reference)
//
#include <hip/hip_runtime.h>
#include <hip/hip_bf16.h>

// LSTM block, fused. Inputs fp32, outputs fp32. bf16 MFMA internally.
// r7 structure + (a) depth-2 A prefetch with NAMED register dbufs (2x-unrolled
// tile loop -> static indices, no scratch), (b) v_cvt_pk_bf16_f32 via inline
// asm (no builtin on gfx950). Weights in registers (Breg 128 VGPR/wave,
// gate-interleaved); one lgkm-only barrier per 32-row tile;
// LDS = A dbuf 32K + c_ex dbuf 16K.

typedef __attribute__((ext_vector_type(8))) short bf16x8;   // 8 bf16 = 4 VGPRs
typedef __attribute__((ext_vector_type(4))) float f32x4;

static __device__ __forceinline__ unsigned short f2bf(float f) {
    unsigned int u = __builtin_bit_cast(unsigned int, f);
    u += 0x7FFFu + ((u >> 16) & 1u);      // RNE
    return (unsigned short)(u >> 16);
}

static __device__ __forceinline__ unsigned int cvtpk(float lo, float hi) {
    unsigned int r;
    asm("v_cvt_pk_bf16_f32 %0, %1, %2" : "=v"(r) : "v"(lo), "v"(hi));
    return r;
}

static __device__ __forceinline__ bf16x8 cvt8(f32x4 a, f32x4 b) {
    union { bf16x8 v; unsigned int w[4]; } r;
    r.w[0] = cvtpk(a[0], a[1]);
    r.w[1] = cvtpk(a[2], a[3]);
    r.w[2] = cvtpk(b[0], b[1]);
    r.w[3] = cvtpk(b[2], b[3]);
    return r.v;
}

static __device__ __forceinline__ float fsig(float x) {
    float e = __builtin_amdgcn_exp2f(-1.44269504f * x);
    return __builtin_amdgcn_rcpf(1.0f + e);
}
static __device__ __forceinline__ float ftanh(float x) {
    float e = __builtin_amdgcn_exp2f(2.8853900818f * x);
    return 1.0f - 2.0f * __builtin_amdgcn_rcpf(e + 1.0f);
}

// ---------------- weight prep: fragment-linear bf16, 16-col gate interleave ----
// WgF: 256 frags of 1KB, frag index = ks*32 + wn*4 + g  (ks 0..7, wn 0..7, g 0..3)
//   lane l: within-gate col = wn*16 + (l&15), k = ks*32 + (l>>4)*8 .. +8
// WchF: 32 frags, index = kt*8 + wn: col = wn*16 + (l&15), k = kt*32 + (l>>4)*8
__global__ void prep_weights(const float* __restrict__ Wf, const float* __restrict__ Wi,
                             const float* __restrict__ Wc, const float* __restrict__ Wo,
                             const float* __restrict__ Wch,
                             unsigned short* __restrict__ WgF,   // 512*256
                             unsigned short* __restrict__ WchF)  // 128*128
{
    int u = blockIdx.x * 256 + threadIdx.x;
    if (u < 16384) {
        int lane = u & 63, g = (u >> 6) & 3, wn = (u >> 8) & 7, ks = u >> 11;
        int l15 = lane & 15, lg = lane >> 4;
        int cg = wn * 16 + l15;
        int k0 = ks * 32 + lg * 8;
        const float* W = (g == 0) ? Wf : (g == 1) ? Wi : (g == 2) ? Wc : Wo;
        union { bf16x8 v; unsigned short s[8]; } r;
#pragma unroll
        for (int i = 0; i < 8; ++i) r.s[i] = f2bf(W[(size_t)(k0 + i) * 128 + cg]);
        *(bf16x8*)(WgF + (size_t)u * 8) = r.v;
    } else if (u < 16384 + 2048) {
        int u2 = u - 16384;
        int lane = u2 & 63, wn = (u2 >> 6) & 7, kt = u2 >> 9;
        int l15 = lane & 15, lg = lane >> 4;
        int col = wn * 16 + l15, k0 = kt * 32 + lg * 8;
        union { bf16x8 v; unsigned short s[8]; } r;
#pragma unroll
        for (int i = 0; i < 8; ++i) r.s[i] = f2bf(Wch[(size_t)(k0 + i) * 128 + col]);
        *(bf16x8*)(WchF + (size_t)u2 * 8) = r.v;
    }
}

// One 32-row tile. CUR = compile-time parity; RI* = raw A(T+1) to stage;
// RO* = raw buffer receiving A(T+2); CIN/COUT = c-input ping-pong.
#define TILE_BODY(T, CUR, RI0,RI1,RI2,RI3, RO0,RO1,RO2,RO3, CIN, COUT)          \
  do {                                                                          \
    const long m0 = base + (long)(T) * 32;                                      \
    /* step1: issue raw A loads for tile (T)+2 */                               \
    if ((T) < 30) {                                                             \
      const float* s_ = asrc + (m0 + 64 + rowA) * 128;                          \
      RO0 = ((const f32x4*)s_)[0]; RO1 = ((const f32x4*)s_)[1];                 \
      RO2 = ((const f32x4*)s_)[2]; RO3 = ((const f32x4*)s_)[3];                 \
    }                                                                           \
    /* step2: c loads for tile (T)+1 */                                         \
    if ((T) < 31) {                                                             \
      _Pragma("unroll")                                                         \
      for (int am = 0; am < 2; ++am)                                            \
        _Pragma("unroll")                                                       \
        for (int r = 0; r < 4; ++r)                                             \
          COUT[am * 4 + r] = cg[(m0 + 32 + am * 16 + lg * 4 + r) * 128 + colc]; \
    }                                                                           \
    /* step3: gates MFMA -- A from LDS buf CUR, B from registers */             \
    {                                                                           \
      const char* ab = lds + (CUR) * 16384;                                     \
      _Pragma("unroll")                                                         \
      for (int ks = 0; ks < 8; ++ks) {                                          \
        bf16x8 af0 = *(const bf16x8*)(ab + ks * 1024 + ((lane * 16) ^ (ks << 4)));       \
        bf16x8 af1 = *(const bf16x8*)(ab + (8 + ks) * 1024 + ((lane * 16) ^ (ks << 4))); \
        _Pragma("unroll")                                                       \
        for (int g_ = 0; g_ < 4; ++g_) {                                        \
          acc[0][g_] = __builtin_amdgcn_mfma_f32_16x16x32_bf16(af0, Breg[ks][g_], acc[0][g_], 0, 0, 0); \
          acc[1][g_] = __builtin_amdgcn_mfma_f32_16x16x32_bf16(af1, Breg[ks][g_], acc[1][g_], 0, 0, 0); \
        }                                                                       \
      }                                                                         \
    }                                                                           \
    /* step4: elementwise -> c_new; store c; bf16 exchange to c_ex buf CUR */   \
    char* cex = lds + 32768 + (CUR) * 8192;                                     \
    _Pragma("unroll")                                                           \
    for (int am = 0; am < 2; ++am)                                              \
      _Pragma("unroll")                                                         \
      for (int r = 0; r < 4; ++r) {                                             \
        float f_  = fsig(acc[am][0][r] + bfb);                                  \
        float i_  = fsig(acc[am][1][r] + bib);                                  \
        float ct_ = ftanh(acc[am][2][r] + bcb);                                 \
        float cv_ = f_ * CIN[am * 4 + r] + i_ * ct_;                            \
        coutp[(m0 + am * 16 + lg * 4 + r) * 128 + colc] = cv_;                  \
        *(unsigned short*)(cex + (am * 4 + (wn >> 1)) * 1024                    \
             + (cslotbase + lg * 4 + r) * 16 + (l15 & 7) * 2) = f2bf(cv_);      \
      }                                                                         \
    /* step5: cvt raw A((T)+1) -> LDS buf CUR^1 */                              \
    if ((T) < 31) {                                                             \
      char* fb = lds + ((CUR) ^ 1) * 16384;                                     \
      *(bf16x8*)(fb + aoff0) = cvt8(RI0, RI1);                                  \
      *(bf16x8*)(fb + aoff1) = cvt8(RI2, RI3);                                  \
    }                                                                           \
    /* step6: single lgkm-only barrier (global prefetch stays in flight) */     \
    asm volatile("s_waitcnt lgkmcnt(0)" ::: "memory");                          \
    __builtin_amdgcn_s_barrier();                                               \
    __builtin_amdgcn_sched_barrier(0);                                          \
    /* step7: GEMM2 (c_ex x Wch-regs) + h epilogue */                           \
    {                                                                           \
      f32x4 acc2_0 = {0.f,0.f,0.f,0.f}, acc2_1 = {0.f,0.f,0.f,0.f};             \
      _Pragma("unroll")                                                         \
      for (int kt = 0; kt < 4; ++kt) {                                          \
        bf16x8 p0 = *(const bf16x8*)(cex + kt * 1024 + lane * 16);              \
        bf16x8 p1 = *(const bf16x8*)(cex + (4 + kt) * 1024 + lane * 16);        \
        acc2_0 = __builtin_amdgcn_mfma_f32_16x16x32_bf16(p0, Wreg[kt], acc2_0, 0, 0, 0); \
        acc2_1 = __builtin_amdgcn_mfma_f32_16x16x32_bf16(p1, Wreg[kt], acc2_1, 0, 0, 0); \
      }                                                                         \
      _Pragma("unroll")                                                         \
      for (int r = 0; r < 4; ++r) {                                             \
        float o0 = fsig(acc[0][3][r] + bob);                                    \
        houtp[(m0 +      lg * 4 + r) * 128 + colc] = o0 * ftanh(acc2_0[r] + bchb); \
        float o1 = fsig(acc[1][3][r] + bob);                                    \
        houtp[(m0 + 16 + lg * 4 + r) * 128 + colc] = o1 * ftanh(acc2_1[r] + bchb); \
      }                                                                         \
    }                                                                           \
    _Pragma("unroll")                                                           \
    for (int am = 0; am < 2; ++am)                                              \
      _Pragma("unroll")                                                         \
      for (int g_ = 0; g_ < 4; ++g_) acc[am][g_] = (f32x4){0.f,0.f,0.f,0.f};    \
  } while (0)

// ---------------- fused kernel: 1024 rows per 512-thread block, 32-row tiles ----
// LDS (48 KB): A frags dbuf [0,16K)+[16K,32K); c_ex dbuf [32K,40K)+[40K,48K)
__global__ __launch_bounds__(512, 2) void lstm_fused(
    const float* __restrict__ xg, const float* __restrict__ hg, const float* __restrict__ cg,
    const float* __restrict__ bfv, const float* __restrict__ biv,
    const float* __restrict__ bcv, const float* __restrict__ bov,
    const float* __restrict__ bchv,
    const unsigned short* __restrict__ WgF, const unsigned short* __restrict__ WchF,
    float* __restrict__ out, int nrows)
{
    __shared__ uint4 lds4[3072];                 // 48 KB
    char* lds = (char*)lds4;

    const int tid  = threadIdx.x;
    const int lane = tid & 63;
    const int wn   = tid >> 6;                   // 0..7: owns cols wn*16..+16 of each gate
    const int l15  = lane & 15;
    const int lg   = lane >> 4;
    const long base = (long)blockIdx.x << 10;    // 1024 rows per block

    float* houtp = out;
    float* coutp = out + (size_t)nrows * 128;

    const int colc = wn * 16 + l15;              // lane-local output column
    const float bfb = bfv[colc], bib = biv[colc], bcb = bcv[colc],
                bob = bov[colc], bchb = bchv[colc];
    const int cslotbase = ((wn & 1) * 2 + (l15 >> 3)) * 16;

    // ---- weights into registers (L2-resident source; read once per block)
    bf16x8 Breg[8][4];                           // [ks][gate] : 128 VGPRs
#pragma unroll
    for (int ks = 0; ks < 8; ++ks)
#pragma unroll
        for (int g = 0; g < 4; ++g)
            Breg[ks][g] = *(const bf16x8*)(WgF + (size_t)((ks * 32 + wn * 4 + g) * 512 + lane * 8));
    bf16x8 Wreg[4];                              // [kt] : 16 VGPRs
#pragma unroll
    for (int kt = 0; kt < 4; ++kt)
        Wreg[kt] = *(const bf16x8*)(WchF + (size_t)((kt * 8 + wn) * 512 + lane * 8));

    // ---- A-staging thread coords (thread stages 16 k-elems of one row)
    const int rowA = tid >> 4;                   // 0..31
    const int kgA  = tid & 15;                   // 16-elem k-group
    const int ksA  = kgA >> 1;
    const int lgA  = (kgA & 1) * 2;
    const int amA  = rowA >> 4;
    const int l15A = rowA & 15;
    const int aoff0 = (amA * 8 + ksA) * 1024 + ((((lgA    ) * 16 + l15A) * 16) ^ (ksA << 4));
    const int aoff1 = (amA * 8 + ksA) * 1024 + ((((lgA + 1) * 16 + l15A) * 16) ^ (ksA << 4));
    const float* asrc = (kgA < 8) ? (xg + kgA * 16) : (hg + (kgA - 8) * 16);

    // ---- prologue: stage A(0) -> LDS buf0; issue raw A(1) -> rA; load c(0) -> c0
    {
        const float* s = asrc + (base + rowA) * 128;
        f32x4 v0 = ((const f32x4*)s)[0], v1 = ((const f32x4*)s)[1],
              v2 = ((const f32x4*)s)[2], v3 = ((const f32x4*)s)[3];
        *(bf16x8*)(lds + aoff0) = cvt8(v0, v1);
        *(bf16x8*)(lds + aoff1) = cvt8(v2, v3);
    }
    f32x4 rA0, rA1, rA2, rA3, rB0, rB1, rB2, rB3;
    {
        const float* s = asrc + (base + 32 + rowA) * 128;
        rA0 = ((const f32x4*)s)[0]; rA1 = ((const f32x4*)s)[1];
        rA2 = ((const f32x4*)s)[2]; rA3 = ((const f32x4*)s)[3];
    }
    float c0[8], c1[8];
#pragma unroll
    for (int am = 0; am < 2; ++am)
#pragma unroll
        for (int r = 0; r < 4; ++r)
            c0[am * 4 + r] = cg[(base + am * 16 + lg * 4 + r) * 128 + colc];
    __syncthreads();

    f32x4 acc[2][4];                             // [am][gate]
#pragma unroll
    for (int am = 0; am < 2; ++am)
#pragma unroll
        for (int g = 0; g < 4; ++g) acc[am][g] = {0.f, 0.f, 0.f, 0.f};

#pragma unroll 1
    for (int t = 0; t < 32; t += 2) {
        TILE_BODY(t,     0, rA0,rA1,rA2,rA3, rB0,rB1,rB2,rB3, c0, c1);
        TILE_BODY(t + 1, 1, rB0,rB1,rB2,rB3, rA0,rA1,rA2,rA3, c1, c0);
    }
}

extern "C" void kernel_launch(void* const* d_in, const int* in_sizes, int n_in,
                              void* d_out, int out_size, void* d_ws, size_t ws_size,
                              hipStream_t stream)
{
    const float* x   = (const float*)d_in[0];
    const float* h   = (const float*)d_in[1];
    const float* c   = (const float*)d_in[2];
    const float* Wf  = (const float*)d_in[3];
    const float* bf_ = (const float*)d_in[4];
    const float* Wi  = (const float*)d_in[5];
    const float* bi_ = (const float*)d_in[6];
    const float* Wc  = (const float*)d_in[7];
    const float* bc_ = (const float*)d_in[8];
    const float* Wo  = (const float*)d_in[9];
    const float* bo_ = (const float*)d_in[10];
    const float* Wch = (const float*)d_in[11];
    const float* bch = (const float*)d_in[12];

    unsigned short* WgF  = (unsigned short*)d_ws;         // 512*256 bf16 fragment-linear
    unsigned short* WchF = WgF + 512 * 256;               // 128*128 bf16 fragment-linear
    float* out = (float*)d_out;

    int nrows = in_sizes[0] / 128;                        // 262144

    prep_weights<<<dim3(72), dim3(256), 0, stream>>>(Wf, Wi, Wc, Wo, Wch, WgF, WchF);
    lstm_fused<<<dim3(nrows / 1024), dim3(512), 0, stream>>>(
        x, h, c, bf_, bi_, bc_, bo_, bch, WgF, WchF, out, nrows);
}